// Round 1
// baseline (303.831 us; speedup 1.0000x reference)
//
#include <hip/hip_runtime.h>

// GCN_84499186582104 — fully fused, one thread per (batch, node).
// B=131072, V=8, NFEAT=32, NHID1=16, NHID12=8, NCLASS=2.
// 32 batches per 256-thread block; nodes of a batch = 8 consecutive lanes.

#define SLOTS 32

__device__ __forceinline__ float grp_max(float x) {
    x = fmaxf(x, __shfl_xor(x, 1));
    x = fmaxf(x, __shfl_xor(x, 2));
    x = fmaxf(x, __shfl_xor(x, 4));
    return x;
}
__device__ __forceinline__ float grp_sum(float x) {
    x += __shfl_xor(x, 1);
    x += __shfl_xor(x, 2);
    x += __shfl_xor(x, 4);
    return x;
}

__global__ __launch_bounds__(256, 4)
void gcn_fused(const float* __restrict__ x,
               const float* __restrict__ adj,
               const float* __restrict__ edge,
               const float* __restrict__ wb, const float* __restrict__ bb,
               const float* __restrict__ w1, const float* __restrict__ b1,
               const float* __restrict__ w2, const float* __restrict__ b2,
               const float* __restrict__ wg, const float* __restrict__ bg,
               const float* __restrict__ wf, const float* __restrict__ bf,
               float* __restrict__ out, int Btot)
{
    // LDS: data exchange between the 8 node-threads of each batch slot.
    // Slot strides 72 / 136 floats: +8 pad -> 2-way bank aliasing only (free).
    __shared__ float FkS[SLOTS * 72];   // Fk[o*8+v]; reused for g2[v*8+n] later
    __shared__ float SS [SLOTS * 72];   // S[o*8+v]
    __shared__ float g1S[SLOTS * 136];  // g1[v*16+j]

    const int tid  = threadIdx.x;
    const int slot = tid >> 3;
    const int v    = tid & 7;
    long long b = (long long)blockIdx.x * SLOTS + slot;
    if (b >= Btot) b = Btot - 1;   // clamp (benign duplicate work); grid is exact anyway

    // ---- global loads for this node (issued up front) ----
    const float* xr = x + (size_t)b * 264 + (size_t)v * 33;
    float xl[33];
#pragma unroll
    for (int i = 0; i < 33; ++i) xl[i] = xr[i];

    const float4* ar = (const float4*)(adj  + (size_t)b * 64 + (size_t)v * 8);
    const float4* er = (const float4*)(edge + (size_t)b * 64 + (size_t)v * 8);
    float4 a0 = ar[0], a1 = ar[1];
    float4 e0 = er[0], e1 = er[1];
    const float type = xl[0];

    // ---- Fk column: Fk[o][v] = bb[o] + dot(feat_v, wb[o,:]) ----
    float Fk[8];
#pragma unroll
    for (int o = 0; o < 8; ++o) {
        float acc = bb[o];
#pragma unroll
        for (int c = 0; c < 32; ++c) acc += xl[1 + c] * wb[o * 32 + c];
        Fk[o] = acc;
    }

    // ---- g1 row: g1[v][j] = dot(feat_v, w1[:,j])  (w1 is [c][j] row-major) ----
    float g1[16];
#pragma unroll
    for (int j = 0; j < 16; ++j) g1[j] = 0.f;
#pragma unroll
    for (int c = 0; c < 32; ++c) {
        const float f = xl[1 + c];
#pragma unroll
        for (int j = 0; j < 16; ++j) g1[j] += f * w1[c * 16 + j];
    }

    // ---- share Fk (column) and g1 (row) ----
#pragma unroll
    for (int o = 0; o < 8; ++o) FkS[slot * 72 + o * 8 + v] = Fk[o];
    {
        float4* gp = (float4*)&g1S[slot * 136 + v * 16];
        gp[0] = make_float4(g1[0],  g1[1],  g1[2],  g1[3]);
        gp[1] = make_float4(g1[4],  g1[5],  g1[6],  g1[7]);
        gp[2] = make_float4(g1[8],  g1[9],  g1[10], g1[11]);
        gp[3] = make_float4(g1[12], g1[13], g1[14], g1[15]);
    }
    __syncthreads();   // A

    // ---- M[o][v] = sum_k Fk[o][k] * Fk[k][v]; softmax over o (thread-local) ----
    float M[8];
#pragma unroll
    for (int o = 0; o < 8; ++o) {
        const float4* fr = (const float4*)&FkS[slot * 72 + o * 8];
        const float4 r0 = fr[0], r1 = fr[1];
        M[o] = r0.x * Fk[0] + r0.y * Fk[1] + r0.z * Fk[2] + r0.w * Fk[3]
             + r1.x * Fk[4] + r1.y * Fk[5] + r1.z * Fk[6] + r1.w * Fk[7];
    }
    float mx = M[0];
#pragma unroll
    for (int o = 1; o < 8; ++o) mx = fmaxf(mx, M[o]);
    float ssum = 0.f;
#pragma unroll
    for (int o = 0; o < 8; ++o) { M[o] = __expf(M[o] - mx); ssum += M[o]; }
    const float sinv = 1.f / ssum;
#pragma unroll
    for (int o = 0; o < 8; ++o) SS[slot * 72 + o * 8 + v] = M[o] * sinv;
    __syncthreads();   // B  (FkS fully read before this point -> reusable)

    // ---- W row: W[v][w] = adj[v][w] * (S[v][w] + edge[v][w]) ----
    const float4* sr = (const float4*)&SS[slot * 72 + v * 8];
    const float4 s0 = sr[0], s1 = sr[1];
    float W[8];
    W[0] = a0.x * (s0.x + e0.x);  W[1] = a0.y * (s0.y + e0.y);
    W[2] = a0.z * (s0.z + e0.z);  W[3] = a0.w * (s0.w + e0.w);
    W[4] = a1.x * (s1.x + e1.x);  W[5] = a1.y * (s1.y + e1.y);
    W[6] = a1.z * (s1.z + e1.z);  W[7] = a1.w * (s1.w + e1.w);

    // ---- layer 1: h = leaky(W @ g1 + b1) ----
    float msg1[16];
#pragma unroll
    for (int j = 0; j < 16; ++j) msg1[j] = 0.f;
#pragma unroll
    for (int w = 0; w < 8; ++w) {
        const float wv = W[w];
        const float4* gp = (const float4*)&g1S[slot * 136 + w * 16];
        const float4 q0 = gp[0], q1 = gp[1], q2 = gp[2], q3 = gp[3];
        msg1[0]  += wv * q0.x; msg1[1]  += wv * q0.y; msg1[2]  += wv * q0.z; msg1[3]  += wv * q0.w;
        msg1[4]  += wv * q1.x; msg1[5]  += wv * q1.y; msg1[6]  += wv * q1.z; msg1[7]  += wv * q1.w;
        msg1[8]  += wv * q2.x; msg1[9]  += wv * q2.y; msg1[10] += wv * q2.z; msg1[11] += wv * q2.w;
        msg1[12] += wv * q3.x; msg1[13] += wv * q3.y; msg1[14] += wv * q3.z; msg1[15] += wv * q3.w;
    }
    float h[16];
#pragma unroll
    for (int j = 0; j < 16; ++j) {
        const float t = msg1[j] + b1[j];
        h[j] = t > 0.f ? t : 0.01f * t;
    }

    // ---- g2 row: g2[v][n] = dot(h_v, w2[:,n])  (w2 is [j][n] row-major) ----
    float g2[8];
#pragma unroll
    for (int n = 0; n < 8; ++n) g2[n] = 0.f;
#pragma unroll
    for (int j = 0; j < 16; ++j) {
        const float hv = h[j];
#pragma unroll
        for (int n = 0; n < 8; ++n) g2[n] += hv * w2[j * 8 + n];
    }
    {
        float4* gp = (float4*)&FkS[slot * 72 + v * 8];   // reuse FkS for g2
        gp[0] = make_float4(g2[0], g2[1], g2[2], g2[3]);
        gp[1] = make_float4(g2[4], g2[5], g2[6], g2[7]);
    }
    __syncthreads();   // C

    // ---- layer 2: h2 = leaky(W @ g2 + b2) ----
    float msg2[8];
#pragma unroll
    for (int n = 0; n < 8; ++n) msg2[n] = 0.f;
#pragma unroll
    for (int w = 0; w < 8; ++w) {
        const float wv = W[w];
        const float4* gp = (const float4*)&FkS[slot * 72 + w * 8];
        const float4 q0 = gp[0], q1 = gp[1];
        msg2[0] += wv * q0.x; msg2[1] += wv * q0.y; msg2[2] += wv * q0.z; msg2[3] += wv * q0.w;
        msg2[4] += wv * q1.x; msg2[5] += wv * q1.y; msg2[6] += wv * q1.z; msg2[7] += wv * q1.w;
    }
    float h2[8];
#pragma unroll
    for (int n = 0; n < 8; ++n) {
        const float t = msg2[n] + b2[n];
        h2[n] = t > 0.f ? t : 0.01f * t;
    }

    // ---- masked attention pooling, t in {0,1}; softmax over v (8 lanes) ----
    float xpool[8];
#pragma unroll
    for (int n = 0; n < 8; ++n) xpool[n] = 0.f;
#pragma unroll
    for (int t = 0; t < 2; ++t) {
        const float tv = (float)t;
        const bool msk = (type == tv);
        float hm[8];
#pragma unroll
        for (int n = 0; n < 8; ++n) hm[n] = msk ? h2[n] : 0.f;
#pragma unroll
        for (int o = 0; o < 8; ++o) {
            float lg = bg[o];
#pragma unroll
            for (int n = 0; n < 8; ++n) lg += hm[n] * wg[o * 8 + n];
            const float m = grp_max(lg);
            const float e = __expf(lg - m);
            const float d = grp_sum(e);
            const float p = grp_sum((e / d) * hm[o]);
            xpool[o] += 0.5f * p;
        }
    }

    // ---- classifier: out[b][n] = bf[n] + dot(xpool, wf[n,:]) ----
    if (v < 2) {
        float r = bf[v];
#pragma unroll
        for (int o = 0; o < 8; ++o) r += xpool[o] * wf[v * 8 + o];
        out[(size_t)b * 2 + v] = r;
    }
}

extern "C" void kernel_launch(void* const* d_in, const int* in_sizes, int n_in,
                              void* d_out, int out_size, void* d_ws, size_t ws_size,
                              hipStream_t stream) {
    const float* x    = (const float*)d_in[0];
    const float* adj  = (const float*)d_in[1];
    const float* edge = (const float*)d_in[2];
    // d_in[3]=wa, d_in[4]=ba are unused by the reference.
    const float* wb   = (const float*)d_in[5];
    const float* bb   = (const float*)d_in[6];
    const float* w1   = (const float*)d_in[7];
    const float* b1   = (const float*)d_in[8];
    const float* w2   = (const float*)d_in[9];
    const float* b2   = (const float*)d_in[10];
    const float* wg   = (const float*)d_in[11];
    const float* bg   = (const float*)d_in[12];
    const float* wf   = (const float*)d_in[13];
    const float* bf   = (const float*)d_in[14];
    float* out = (float*)d_out;

    const int Btot = in_sizes[0] / 264;          // B = 131072
    const int grid = (Btot + SLOTS - 1) / SLOTS; // 4096 blocks

    gcn_fused<<<grid, 256, 0, stream>>>(x, adj, edge, wb, bb, w1, b1, w2, b2,
                                        wg, bg, wf, bf, out, Btot);
}